// Round 6
// baseline (1222.699 us; speedup 1.0000x reference)
//
#include <hip/hip_runtime.h>
#include <hip/hip_bf16.h>
#include <math.h>
#include <stdint.h>

#define D_MODEL 2048
#define D_FF    8192
#define MTOK    16384   // 4 * 4096 tokens
#define NW      (D_FF * D_MODEL)   // elements per weight matrix

typedef int    i32x4  __attribute__((ext_vector_type(4)));
typedef __bf16 bf16x8 __attribute__((ext_vector_type(8)));

// width-16 async global->LDS (per-lane global addr, wave-uniform LDS base + lane*16)
#define GLOAD_LDS16(gp, lp)                                                   \
  __builtin_amdgcn_global_load_lds(                                           \
      (__attribute__((address_space(1))) void*)(gp),                          \
      (__attribute__((address_space(3))) void*)(lp), 16, 0, 0)

// ---------------- stage 1: deterministic double partial sums of |w| ----------------
__global__ void absum_s1(const float* __restrict__ w1, const float* __restrict__ w2,
                         double* __restrict__ partials) {
    const float* w = blockIdx.y ? w2 : w1;
    __shared__ double sm[256];
    int tid = blockIdx.x * 256 + threadIdx.x;
    double s = 0.0;
    for (int i = tid; i < NW / 4; i += 1024 * 256) {
        float4 v = ((const float4*)w)[i];
        s += (double)fabsf(v.x) + (double)fabsf(v.y) + (double)fabsf(v.z) + (double)fabsf(v.w);
    }
    sm[threadIdx.x] = s;
    __syncthreads();
    for (int off = 128; off > 0; off >>= 1) {
        if (threadIdx.x < off) sm[threadIdx.x] += sm[threadIdx.x + off];
        __syncthreads();
    }
    if (threadIdx.x == 0) partials[blockIdx.y * 1024 + blockIdx.x] = sm[0];
}

// ---------------- stage 2: 1024 partials -> float threshold 0.7*mean ----------------
__global__ void absum_s2(const double* __restrict__ partials, float* __restrict__ thr) {
    __shared__ double sm[256];
    for (int wsel = 0; wsel < 2; ++wsel) {
        const double* p = partials + wsel * 1024;
        double s = p[threadIdx.x] + p[threadIdx.x + 256] + p[threadIdx.x + 512] + p[threadIdx.x + 768];
        sm[threadIdx.x] = s;
        __syncthreads();
        for (int off = 128; off > 0; off >>= 1) {
            if (threadIdx.x < off) sm[threadIdx.x] += sm[threadIdx.x + off];
            __syncthreads();
        }
        if (threadIdx.x == 0) thr[wsel] = (float)(0.7 * (sm[0] / (double)NW));
        __syncthreads();
    }
}

// ---------------- w1 -> ternary i8, elementwise ----------------
__global__ void quantw1(const float* __restrict__ w, const float* __restrict__ thr,
                        int8_t* __restrict__ q) {
    float t = thr[0];
    int i = (blockIdx.x * 256 + threadIdx.x) * 4;
    float4 v = *(const float4*)(w + i);
    char4 o;
    o.x = (fabsf(v.x) >= t) ? (v.x > 0.f ? 1 : -1) : 0;
    o.y = (fabsf(v.y) >= t) ? (v.y > 0.f ? 1 : -1) : 0;
    o.z = (fabsf(v.z) >= t) ? (v.z > 0.f ? 1 : -1) : 0;
    o.w = (fabsf(v.w) >= t) ? (v.w > 0.f ? 1 : -1) : 0;
    *(char4*)(q + i) = o;
}

// ---------------- w2 -> ternary i8, one block per row, + row sums (colsum) ---------
__global__ void quantw2(const float* __restrict__ w, const float* __restrict__ thr,
                        int8_t* __restrict__ q, float* __restrict__ colsum) {
    __shared__ int sm[256];
    float t = thr[1];
    const int row = blockIdx.x;
    const int tid = threadIdx.x;
    int isum = 0;
    #pragma unroll
    for (int j = 0; j < 8; ++j) {
        int idx = row * D_FF + j * 1024 + tid * 4;
        float4 v = *(const float4*)(w + idx);
        char4 o;
        o.x = (fabsf(v.x) >= t) ? (v.x > 0.f ? 1 : -1) : 0;
        o.y = (fabsf(v.y) >= t) ? (v.y > 0.f ? 1 : -1) : 0;
        o.z = (fabsf(v.z) >= t) ? (v.z > 0.f ? 1 : -1) : 0;
        o.w = (fabsf(v.w) >= t) ? (v.w > 0.f ? 1 : -1) : 0;
        isum += o.x + o.y + o.z + o.w;
        *(char4*)(q + idx) = o;
    }
    sm[tid] = isum;
    __syncthreads();
    for (int off = 128; off > 0; off >>= 1) {
        if (tid < off) sm[tid] += sm[tid + off];
        __syncthreads();
    }
    if (tid == 0) colsum[row] = (float)sm[0];
}

// ---------------- x -> per-row symmetric i8, one block per token row ----------------
__global__ void xquant(const float* __restrict__ x, int8_t* __restrict__ xq,
                       float* __restrict__ sx) {
    __shared__ float sm[256];
    const int row = blockIdx.x;
    const int tid = threadIdx.x;
    float4 v[2];
    float mx = 0.f;
    #pragma unroll
    for (int j = 0; j < 2; ++j) {
        v[j] = *(const float4*)(x + (size_t)row * D_MODEL + j * 1024 + tid * 4);
        mx = fmaxf(mx, fmaxf(fmaxf(fabsf(v[j].x), fabsf(v[j].y)),
                             fmaxf(fabsf(v[j].z), fabsf(v[j].w))));
    }
    sm[tid] = mx;
    __syncthreads();
    for (int off = 128; off > 0; off >>= 1) {
        if (tid < off) sm[tid] = fmaxf(sm[tid], sm[tid + off]);
        __syncthreads();
    }
    float m = sm[0];
    float inv = (m > 0.f) ? 127.f / m : 0.f;
    if (tid == 0) sx[row] = (m > 0.f) ? m / 127.f : 0.f;
    #pragma unroll
    for (int j = 0; j < 2; ++j) {
        char4 o;
        o.x = (int8_t)min(127, max(-127, __float2int_rn(v[j].x * inv)));
        o.y = (int8_t)min(127, max(-127, __float2int_rn(v[j].y * inv)));
        o.z = (int8_t)min(127, max(-127, __float2int_rn(v[j].z * inv)));
        o.w = (int8_t)min(127, max(-127, __float2int_rn(v[j].w * inv)));
        *(char4*)(xq + (size_t)row * D_MODEL + j * 1024 + tid * 4) = o;
    }
}

// ---------------- gelu(h) bf16 -> per-row ASYMMETRIC i8 (zero-point via colsum) -----
__global__ void hquant(const __bf16* __restrict__ h, int8_t* __restrict__ hq,
                       float2* __restrict__ sh) {
    __shared__ float sm[256];
    const int row = blockIdx.x;
    const int tid = threadIdx.x;
    const float gmin = -0.17f;
    float vals[4][8];
    float mx = -1e30f;
    #pragma unroll
    for (int j = 0; j < 4; ++j) {
        bf16x8 b = *(const bf16x8*)(h + (size_t)row * D_FF + j * 2048 + tid * 8);
        #pragma unroll
        for (int e = 0; e < 8; ++e) {
            float f = (float)b[e];
            vals[j][e] = f;
            mx = fmaxf(mx, f);
        }
    }
    sm[tid] = mx;
    __syncthreads();
    for (int off = 128; off > 0; off >>= 1) {
        if (tid < off) sm[tid] = fmaxf(sm[tid], sm[tid + off]);
        __syncthreads();
    }
    float M = sm[0];
    float s = (M - gmin) / 254.f;
    float inv = 254.f / (M - gmin);
    if (tid == 0) sh[row] = make_float2(s, 127.f * s + gmin);
    #pragma unroll
    for (int j = 0; j < 4; ++j) {
        char4 o0, o1;
        int q[8];
        #pragma unroll
        for (int e = 0; e < 8; ++e)
            q[e] = min(127, max(-127, __float2int_rn((vals[j][e] - gmin) * inv) - 127));
        o0.x = q[0]; o0.y = q[1]; o0.z = q[2]; o0.w = q[3];
        o1.x = q[4]; o1.y = q[5]; o1.z = q[6]; o1.w = q[7];
        int8_t* p = hq + (size_t)row * D_FF + j * 2048 + tid * 8;
        *(char4*)p = o0;
        *(char4*)(p + 4) = o1;
    }
}

// ===================================================================================
// 128x128 i8 MFMA GEMM — cross-iteration register double-buffer (convoy fix).
//   C = A[M,K] * B[N,K]^T ; 256 threads = 4 waves (2M x 2N), per-wave 64x64.
//   R2/R5 post-mortem: one-barrier read-then-MFMA loops convoy — each wave's MFMA
//   cluster waits on its own read storm (same-iteration lgkm), and the 2 blocks
//   phase-lock via shared-pipe contention -> LDS and MFMA pipes SERIALIZE
//   (1306 MFMA + 1920 LDS + sync = 3910 cyc measured, both pipes <50% busy).
//   Fix: read stage s+1 fragments into NEXT regs during stage s MFMAs; consumers
//   are one iteration away, so lgkm latency is fully hidden per-wave and the two
//   pipes overlap by construction. Requires stage s+1 landed at iter s START ->
//   ring-4 LDS (stage 16 KiB = A[128][64]+B[128][64]; 64 KiB total -> 2 blocks/CU),
//   counted s_waitcnt vmcnt(4) (stage s+3's 4 loads stay in flight across every
//   barrier), ONE s_barrier per iter.
//   16B chunk c of row r stored at slot c^((r>>1)&3): frag reads 2-way = free
//   (identical byte pattern to R2, measured SQ_LDS_BANK_CONFLICT == 0).
// EPI==0 (fc1): h[m,n] = bf16( gelu( rs[m]*acc + bias[n] ) ), epilogue staged via
//   LDS and written as 16B coalesced stores (direct 2B stores half-filled cache
//   lines: WRITE_SIZE 523 MB vs 256 ideal).
// EPI==1 (fc2): out = rs2[m].x*acc + rs2[m].y*colsum[n] + bias[n] (f32 stores
//   already fill 64B lines -> direct).
// Both: XCD-burst map — XCD owns 16 consecutive by-rows, 4-by bursts bx-major
//   (B panel L2-reuse; FETCH 557->246 MB measured R4/R5).
// ===================================================================================
template<int EPI>
__global__ __launch_bounds__(256, 2) void gemm_i8_bt(
    const int8_t* __restrict__ A,    // [M,K]
    const int8_t* __restrict__ B,    // [N,K]
    const float*  __restrict__ bias, // [N]
    const float*  __restrict__ rs,   // fc1: sx[M] ; fc2: (float2*)sh[M]
    const float*  __restrict__ colsum, // fc2 only: [N]
    void* __restrict__ Cout,
    int M, int N, int K)
{
    __shared__ int8_t Sh[4 * 16384];   // ring-4: per stage A[128][64] + B[128][64]

    const int tid  = threadIdx.x;
    const int wave = tid >> 6;
    const int lane = tid & 63;
    const int quad = lane >> 4;
    const int l15  = lane & 15;
    const int wm   = (wave >> 1) * 64;    // 2 wave-rows of M
    const int wn   = (wave & 1) * 64;     // 2 wave-cols of N

    // ---- block -> tile map: XCD x owns by in [x*16,x*16+16), 4-by bursts, bx-major
    const int gx   = gridDim.x;           // fc1: 64, fc2: 16
    const int orig = blockIdx.y * gx + blockIdx.x;
    const int xcd  = orig & 7;
    const int l    = orig >> 3;
    const int stsh = (EPI == 0) ? 8 : 6;  // log2(4*gx)
    const int st   = l >> stsh;           // supertile [0,4) per XCD
    const int r    = l & ((1 << stsh) - 1);
    const int by   = xcd * 16 + st * 4 + (r & 3);
    const int bx   = r >> 2;
    const int m0 = by << 7;   // *128
    const int n0 = bx << 7;   // *128

    i32x4 acc[4][4] = {};

    // ---- staging: per stage, A = 512 16B chunks (2/thread), B = 512 (2/thread) ----
    const int8_t* gA[2]; const int8_t* gB[2];
    char* dA[2]; char* dB[2];
    char* const ldsb = (char*)Sh;
    #pragma unroll
    for (int it = 0; it < 2; ++it) {
        int slot = it * 256 + tid;            // [0,512)
        int row  = slot >> 2;                 // [0,128)
        int cg   = (slot & 3) ^ ((row >> 1) & 3);
        gA[it] = A + (size_t)(m0 + row) * K + cg * 16;
        gB[it] = B + (size_t)(n0 + row) * K + cg * 16;
        dA[it] = ldsb + it * 4096 + wave * 1024;          // + lane*16 by HW
        dB[it] = ldsb + 8192 + it * 4096 + wave * 1024;
    }

    // ---- per-thread fragment LDS offsets (within a stage) ----
    int aoff[4], boff[4];
    #pragma unroll
    for (int f = 0; f < 4; ++f) {
        int ra = wm + f * 16 + l15;
        aoff[f] = ra * 64 + ((quad ^ ((ra >> 1) & 3)) << 4);
        int rb = wn + f * 16 + l15;
        boff[f] = 8192 + rb * 64 + ((quad ^ ((rb >> 1) & 3)) << 4);
    }

    const int NH = K >> 6;     // BK=64 stages (fc1: 32, fc2: 128)
    const int STG = 16384;

    // ---- prologue: issue stages 0,1,2 (12 loads); wait stages 0,1 landed ----
    #pragma unroll
    for (int h = 0; h < 3; ++h) {
        #pragma unroll
        for (int it = 0; it < 2; ++it) {
            GLOAD_LDS16(gA[it], dA[it] + h * STG);
            GLOAD_LDS16(gB[it], dB[it] + h * STG);
            gA[it] += 64; gB[it] += 64;
        }
    }
    asm volatile("s_waitcnt vmcnt(4)" ::: "memory");
    __builtin_amdgcn_s_barrier();
    __builtin_amdgcn_sched_barrier(0);

    // pre-read frags(0)
    i32x4 af[4], bfr[4];
    #pragma unroll
    for (int f = 0; f < 4; ++f) {
        af[f]  = *(const i32x4*)(ldsb + aoff[f]);
        bfr[f] = *(const i32x4*)(ldsb + boff[f]);
    }

    for (int s = 0; s < NH; ++s) {
        const int roff_n = ((s + 1) & 3) * STG;   // slot of stage s+1 (read next)
        const int soff   = ((s + 3) & 3) * STG;   // slot of stage s+3 (being filled)
        // issue stage s+3 loads (earliest HBM start; slot s-1, drained of readers)
        if (s + 3 < NH) {
            #pragma unroll
            for (int it = 0; it < 2; ++it) {
                GLOAD_LDS16(gA[it], ldsb + soff + (dA[it] - ldsb));
                GLOAD_LDS16(gB[it], ldsb + soff + (dB[it] - ldsb));
                gA[it] += 64; gB[it] += 64;
            }
        }
        // read NEXT iteration's fragments (consumers one iter away -> no lgkm stall)
        i32x4 afn[4], bfn[4];
        if (s + 1 < NH) {
            #pragma unroll
            for (int f = 0; f < 4; ++f) {
                afn[f] = *(const i32x4*)(ldsb + roff_n + aoff[f]);
                bfn[f] = *(const i32x4*)(ldsb + roff_n + boff[f]);
            }
        }
        // MFMA over current regs
        __builtin_amdgcn_s_setprio(1);
        #pragma unroll
        for (int mf = 0; mf < 4; ++mf)
            #pragma unroll
            for (int nf = 0; nf < 4; ++nf)
                acc[mf][nf] = __builtin_amdgcn_mfma_i32_16x16x64_i8(
                    af[mf], bfr[nf], acc[mf][nf], 0, 0, 0);
        __builtin_amdgcn_s_setprio(0);
        #pragma unroll
        for (int f = 0; f < 4; ++f) { af[f] = afn[f]; bfr[f] = bfn[f]; }
        // boundary: ensure stage s+2 landed; keep stage s+3 (4 loads) in flight
        if (s < NH - 1) {
            __builtin_amdgcn_sched_barrier(0);
            if (s + 3 < NH) { asm volatile("s_waitcnt vmcnt(4)" ::: "memory"); }
            else            { asm volatile("s_waitcnt vmcnt(0)" ::: "memory"); }
            __builtin_amdgcn_s_barrier();
            __builtin_amdgcn_sched_barrier(0);
        }
    }

    if (EPI == 0) {
        // ---- fc1 epilogue: stage bf16 tile in LDS, then 16B coalesced stores ----
        __builtin_amdgcn_s_barrier();   // all waves done with ring reads
        char* Cs = ldsb;                // 128 rows x 272 B pitch = 34 KiB
        #pragma unroll
        for (int nf = 0; nf < 4; ++nf) {
            const int n = n0 + wn + nf * 16 + l15;
            const float bv = bias[n];
            #pragma unroll
            for (int mf = 0; mf < 4; ++mf)
                #pragma unroll
                for (int r = 0; r < 4; ++r) {
                    int mloc = wm + mf * 16 + quad * 4 + r;
                    float v = rs[m0 + mloc] * (float)acc[mf][nf][r] + bv;
                    v = 0.5f * v * (1.0f + erff(v * 0.70710678118654752f));
                    *(__bf16*)(Cs + mloc * 272 + (wn + nf * 16 + l15) * 2) = (__bf16)v;
                }
        }
        __builtin_amdgcn_s_barrier();
        const int rr = tid >> 1, hh = tid & 1;
        const char* src = Cs + rr * 272 + hh * 128;
        __bf16* dst = (__bf16*)Cout + (size_t)(m0 + rr) * N + n0 + hh * 64;
        #pragma unroll
        for (int j = 0; j < 8; ++j)
            *(i32x4*)(dst + j * 8) = *(const i32x4*)(src + j * 16);
    } else {
        // ---- fc2 epilogue: f32 stores, 16 lanes x 4B = full 64B lines ----
        #pragma unroll
        for (int nf = 0; nf < 4; ++nf) {
            const int n = n0 + wn + nf * 16 + l15;
            const float bv = bias[n];
            const float cs = colsum[n];
            #pragma unroll
            for (int mf = 0; mf < 4; ++mf)
                #pragma unroll
                for (int r = 0; r < 4; ++r) {
                    int m = m0 + wm + mf * 16 + quad * 4 + r;
                    float2 so = ((const float2*)rs)[m];
                    ((float*)Cout)[(size_t)m * N + n] =
                        so.x * (float)acc[mf][nf][r] + so.y * cs + bv;
                }
        }
    }
}

extern "C" void kernel_launch(void* const* d_in, const int* in_sizes, int n_in,
                              void* d_out, int out_size, void* d_ws, size_t ws_size,
                              hipStream_t stream) {
    const float* x  = (const float*)d_in[0];
    const float* w1 = (const float*)d_in[1];
    const float* b1 = (const float*)d_in[2];
    const float* w2 = (const float*)d_in[3];
    const float* b2 = (const float*)d_in[4];
    float* out = (float*)d_out;

    char* ws = (char*)d_ws;
    float*  thr = (float*)ws;
    float*  sx  = (float*)(ws + 256);
    float2* sh  = (float2*)(ws + 256 + (64 << 10));
    float*  colsum = (float*)(ws + 256 + (192 << 10));
    int8_t* xq  = (int8_t*)(ws + 256 + (256 << 10));
    int8_t* w1q = xq  + (size_t)MTOK * D_MODEL;
    int8_t* w2q = w1q + (size_t)D_FF * D_MODEL;
    int8_t* hq  = w2q + (size_t)D_MODEL * D_FF;
    __bf16* h   = (__bf16*)(hq + (size_t)MTOK * D_FF);
    double* partials = (double*)h;   // 16 KiB, consumed before h is written

    absum_s1<<<dim3(1024, 2), 256, 0, stream>>>(w1, w2, partials);
    absum_s2<<<1, 256, 0, stream>>>(partials, thr);

    quantw1<<<NW / 1024, 256, 0, stream>>>(w1, thr, w1q);
    quantw2<<<D_MODEL, 256, 0, stream>>>(w2, thr, w2q, colsum);
    xquant<<<MTOK, 256, 0, stream>>>(x, xq, sx);

    dim3 g1(D_FF / 128, MTOK / 128);     // (64, 128)
    gemm_i8_bt<0><<<g1, 256, 0, stream>>>(xq, w1q, b1, sx, nullptr, (void*)h,
                                          MTOK, D_FF, D_MODEL);

    hquant<<<MTOK, 256, 0, stream>>>(h, hq, sh);

    dim3 g2(D_MODEL / 128, MTOK / 128);  // (16, 128)
    gemm_i8_bt<1><<<g2, 256, 0, stream>>>(hq, w2q, b2, (const float*)sh, colsum, (void*)out,
                                          MTOK, D_MODEL, D_FF);
}